// Round 5
// baseline (168.286 us; speedup 1.0000x reference)
//
#include <hip/hip_runtime.h>
#include <math.h>

#define BB 2
#define SS 2048
#define DD 64
#define HH 12
#define CFIX 16.0f

typedef _Float16 v8h __attribute__((ext_vector_type(8)));
typedef short    v8s __attribute__((ext_vector_type(8)));
typedef short    v4s __attribute__((ext_vector_type(4)));
typedef float    v4f __attribute__((ext_vector_type(4)));

__device__ __forceinline__ unsigned short f2bf(float f) {
    unsigned u = __float_as_uint(f);
    u += 0x7FFF + ((u >> 16) & 1);          // RTN-even
    return (unsigned short)(u >> 16);
}
__device__ __forceinline__ unsigned short f2bf_trunc(float f) {
    return (unsigned short)(__float_as_uint(f) >> 16);   // p>=0; truncation bias cancels in o/l
}

__device__ __forceinline__ void async16(const void* g, void* l) {
    __builtin_amdgcn_global_load_lds(
        (const __attribute__((address_space(1))) unsigned int*)g,
        (__attribute__((address_space(3))) unsigned int*)l, 16, 0, 0);
}

// ---------------------------------------------------------------------------
// Kernel 1: fused QKV projection (+ WoT prep folded in).
// Outputs: Q16,K16 fp16 [bh][s][64]; VT bf16 [bh][d][s]; WoT fp16 [64][768].
// ---------------------------------------------------------------------------
__global__ __launch_bounds__(256) void qkv_kernel(
    const float* __restrict__ x,
    const float* __restrict__ Wq, const float* __restrict__ bq,
    const float* __restrict__ Wk, const float* __restrict__ bk,
    const float* __restrict__ Wv, const float* __restrict__ bv,
    const float* __restrict__ Wo, _Float16* __restrict__ WoT,
    _Float16* __restrict__ Q16, _Float16* __restrict__ K16,
    unsigned short* __restrict__ VT)
{
    __shared__ float xs[16 * 64];
    const int rBase = blockIdx.x * 16;
    const int cg    = blockIdx.y;
    const int mat   = cg / 3;
    const int col   = (cg % 3) * 256 + threadIdx.x;

    // folded prep: transpose+convert Wo (768x64 -> WoT[64][768])
    if (cg == 0 && blockIdx.x < 192) {
        int e = blockIdx.x * 256 + threadIdx.x;     // < 49152
        int k = e >> 6, c2 = e & 63;
        WoT[c2 * 768 + k] = (_Float16)Wo[e];
    }

    const float* W    = (mat == 0) ? Wq : (mat == 1) ? Wk : Wv;
    const float* bias = (mat == 0) ? bq : (mat == 1) ? bk : bv;

    for (int i = threadIdx.x; i < 16 * 64; i += 256)
        xs[i] = x[rBase * 64 + i];
    __syncthreads();

    float acc[16];
#pragma unroll
    for (int r = 0; r < 16; r++) acc[r] = 0.f;

    for (int k = 0; k < 64; k++) {
        float w = W[k * 768 + col];
#pragma unroll
        for (int r = 0; r < 16; r++) acc[r] += xs[r * 64 + k] * w;
    }

    const float bb = bias[col];
    const int h = col >> 6, d = col & 63;

    if (mat < 2) {
        _Float16* Out = (mat == 0) ? Q16 : K16;
#pragma unroll
        for (int r = 0; r < 16; r++) {
            int row = rBase + r;
            int b = row >> 11, s = row & 2047;
            Out[(((size_t)b * HH + h) * SS + s) * 64 + d] = (_Float16)(acc[r] + bb);
        }
    } else {
        const int b = rBase >> 11, s0 = rBase & 2047;   // 16 | 2048: no straddle
        unsigned short tmp[16];
#pragma unroll
        for (int r = 0; r < 16; r++) tmp[r] = f2bf(acc[r] + bb);
        size_t base = ((size_t)(b * HH + h) * 64 + d) * SS + s0;
        v8s w0, w1;
#pragma unroll
        for (int r = 0; r < 8; r++) { w0[r] = (short)tmp[r]; w1[r] = (short)tmp[r + 8]; }
        *(v8s*)&VT[base]     = w0;
        *(v8s*)&VT[base + 8] = w1;
    }
}

// ---------------------------------------------------------------------------
// Kernel 2: MFMA flash attention, fixed-C softmax, key-split waves.
// Block = 4 waves over 32 q rows: wave = (rowg = w&1 [16 rows], keyh = w>>1
// [32 of the 64 staged keys]). Partial (o,l) merged in epilogue (fixed-C
// softmax makes key partitions additive). Grid (64, 24), long qtiles first.
// ---------------------------------------------------------------------------
__global__ __launch_bounds__(256) void attn_kernel(
    const _Float16* __restrict__ Q16, const _Float16* __restrict__ K16,
    const unsigned short* __restrict__ VTg, _Float16* __restrict__ O16)
{
    __shared__ __align__(16) _Float16       Kl[2][64 * 64];   // [key][d], xor-swizzled
    __shared__ __align__(16) unsigned short Vl[2][64 * 64];   // [d][key], xor-swizzled
    __shared__ __align__(16) unsigned short Pl[4][16 * 36];   // stride 36: aligned + ~conflict-free

    const int bh    = blockIdx.y;
    const int qtile = 63 - blockIdx.x;           // long blocks dispatch first
    const int qBase = qtile * 32;
    const int wave  = threadIdx.x >> 6;
    const int lane  = threadIdx.x & 63;
    const int llow  = lane & 15;
    const int quad  = lane >> 4;
    const int rowg  = wave & 1;
    const int keyh  = wave >> 1;
    const int q0    = qBase + rowg * 16;

    const _Float16*       Kp = K16 + (size_t)bh * SS * 64;
    const unsigned short* Vp = VTg + (size_t)bh * 64 * SS;

    const _Float16* Qp = Q16 + ((size_t)bh * SS + q0) * 64;
    v8h qa0 = *(const v8h*)(Qp + llow * 64 + quad * 8);
    v8h qa1 = *(const v8h*)(Qp + llow * 64 + 32 + quad * 8);

    v4f o[4];
    float lacc[4] = {0.f, 0.f, 0.f, 0.f};
#pragma unroll
    for (int nb = 0; nb < 4; nb++) o[nb] = (v4f){0.f, 0.f, 0.f, 0.f};

    const int nt = qtile / 2 + 1;   // keys needed: <= 32*qtile+31 -> floor(qtile/2)+1 tiles

    // prefetch tile 0 into buf 0 (wave-uniform base + lane*16 dest, per DMA rule)
#pragma unroll
    for (int rep = 0; rep < 2; rep++) {
        int c = rep * 256 + threadIdx.x;
        int row = c >> 3, g = (c & 7) ^ (row & 7);
        async16(Kp + (size_t)row * 64 + g * 8, &Kl[0][(rep * 256 + wave * 64) * 8]);
        async16(Vp + (size_t)row * SS + g * 8, &Vl[0][(rep * 256 + wave * 64) * 8]);
    }

    for (int t = 0; t < nt; t++) {
        __syncthreads();                 // drains this tile's DMA
        if (t + 1 < nt) {                // prefetch AFTER barrier -> overlaps compute
            const int ktn = (t + 1) * 64, bufn = (t + 1) & 1;
#pragma unroll
            for (int rep = 0; rep < 2; rep++) {
                int c = rep * 256 + threadIdx.x;
                int row = c >> 3, g = (c & 7) ^ (row & 7);
                async16(Kp + (size_t)(ktn + row) * 64 + g * 8,
                        &Kl[bufn][(rep * 256 + wave * 64) * 8]);
                async16(Vp + (size_t)row * SS + ktn + g * 8,
                        &Vl[bufn][(rep * 256 + wave * 64) * 8]);
            }
        }
        const int buf = t & 1, kt = t * 64;
        const int sw = llow & 7;

        // ---- QK^T over this wave's 32-key half: 2 col-blocks of 16 ----
        v4f sc[2];
#pragma unroll
        for (int cb = 0; cb < 2; cb++) {
            const int rk = 32 * keyh + 16 * cb + llow;
            v8h k0 = *(const v8h*)&Kl[buf][rk * 64 + ((quad ^ sw)) * 8];
            v8h k1 = *(const v8h*)&Kl[buf][rk * 64 + (((4 + quad) ^ sw)) * 8];
            v4f a = (v4f){0.f, 0.f, 0.f, 0.f};
            a = __builtin_amdgcn_mfma_f32_16x16x32_f16(qa0, k0, a, 0, 0, 0);
            a = __builtin_amdgcn_mfma_f32_16x16x32_f16(qa1, k1, a, 0, 0, 0);
            sc[cb] = a;
        }

        // ---- mask folded into exp select; fixed-C; P write ----
#pragma unroll
        for (int cb = 0; cb < 2; cb++) {
            const int key = kt + 32 * keyh + 16 * cb + llow;
#pragma unroll
            for (int r = 0; r < 4; r++) {
                const int row = q0 + quad * 4 + r;
                const float sv = sc[cb][r];
                const float e  = __expf(sv - CFIX);
                const float p  = (key <= row && sv != 0.f) ? e : 0.f;  // faithful quirky mask
                lacc[r] += p;
                Pl[wave][(quad * 4 + r) * 36 + 16 * cb + llow] = f2bf_trunc(p);
            }
        }

        // ---- P: C-layout -> A-layout via per-wave LDS tile ----
        v8s pa;
        {
            v4s a0 = *(const v4s*)&Pl[wave][llow * 36 + quad * 8];
            v4s a1 = *(const v4s*)&Pl[wave][llow * 36 + quad * 8 + 4];
#pragma unroll
            for (int j = 0; j < 4; j++) { pa[j] = a0[j]; pa[j + 4] = a1[j]; }
        }

        // ---- PV over the 32-key half (bf16) ----
#pragma unroll
        for (int nb = 0; nb < 4; nb++) {
            const int rv = 16 * nb + llow;                       // rv&7 == sw
            v8s vv = *(const v8s*)&Vl[buf][rv * 64 + (((4 * keyh + quad) ^ sw)) * 8];
            o[nb] = __builtin_amdgcn_mfma_f32_16x16x32_bf16(pa, vv, o[nb], 0, 0, 0);
        }
    }

    // ---- epilogue ----
    // lacc[r] is a per-lane PARTIAL (keys == llow mod 16 of this wave's half):
    // reduce over the 16-lane group first (this was the R4 NaN bug).
#pragma unroll
    for (int r = 0; r < 4; r++) {
        lacc[r] += __shfl_xor(lacc[r], 1);
        lacc[r] += __shfl_xor(lacc[r], 2);
        lacc[r] += __shfl_xor(lacc[r], 4);
        lacc[r] += __shfl_xor(lacc[r], 8);
    }

    // merge key-halves via LDS (reuse K/V buffers), write O
    __syncthreads();                                  // last tile's LDS reads done
    float* redO = (float*)&Kl[0][0];                  // [32 rows][stride 68]
    float* redL = (float*)&Vl[0][0];                  // [32 rows]
    if (keyh == 1) {
#pragma unroll
        for (int nb = 0; nb < 4; nb++)
#pragma unroll
            for (int r = 0; r < 4; r++)
                redO[(rowg * 16 + quad * 4 + r) * 68 + 16 * nb + llow] = o[nb][r];
        if (llow == 0) {
#pragma unroll
            for (int r = 0; r < 4; r++)
                redL[rowg * 16 + quad * 4 + r] = lacc[r];     // full row sum (reduced above)
        }
    }
    __syncthreads();
    if (keyh == 0) {
        _Float16* Op = O16 + ((size_t)bh * SS + q0) * 64;
#pragma unroll
        for (int r = 0; r < 4; r++)
            lacc[r] += redL[rowg * 16 + quad * 4 + r];
#pragma unroll
        for (int nb = 0; nb < 4; nb++)
#pragma unroll
            for (int r = 0; r < 4; r++) {
                float v = o[nb][r] + redO[(rowg * 16 + quad * 4 + r) * 68 + 16 * nb + llow];
                Op[(quad * 4 + r) * 64 + 16 * nb + llow] = (_Float16)(v / lacc[r]);
            }
    }
}

// ---------------------------------------------------------------------------
// Kernel 3: output projection via MFMA (unchanged from R3).
// ---------------------------------------------------------------------------
__global__ __launch_bounds__(256) void out_kernel(
    const _Float16* __restrict__ O16, const _Float16* __restrict__ WoT,
    const float* __restrict__ bo, float* __restrict__ out)
{
    __shared__ __align__(16) float red[4][16][66];
    const int r0   = blockIdx.x * 16;
    const int wave = threadIdx.x >> 6, lane = threadIdx.x & 63;
    const int llow = lane & 15, quad = lane >> 4;
    const int b = r0 >> 11, s = r0 & 2047;          // 16 | 2048: no straddle

    v4f acc[4];
#pragma unroll
    for (int cb = 0; cb < 4; cb++) acc[cb] = (v4f){0.f, 0.f, 0.f, 0.f};

#pragma unroll
    for (int i = 0; i < 6; i++) {
        const int kb = wave * 6 + i;                // 0..23
        const int h = kb >> 1, dseg = (kb & 1) * 32;
        v8h af = *(const v8h*)(O16 + ((size_t)(b * HH + h) * SS + s + llow) * 64 + dseg + quad * 8);
#pragma unroll
        for (int cb = 0; cb < 4; cb++) {
            v8h bf = *(const v8h*)(WoT + (size_t)(16 * cb + llow) * 768 + kb * 32 + quad * 8);
            acc[cb] = __builtin_amdgcn_mfma_f32_16x16x32_f16(af, bf, acc[cb], 0, 0, 0);
        }
    }

#pragma unroll
    for (int cb = 0; cb < 4; cb++)
#pragma unroll
        for (int r = 0; r < 4; r++)
            red[wave][quad * 4 + r][16 * cb + llow] = acc[cb][r];
    __syncthreads();

    const int col = threadIdx.x & 63, rr = threadIdx.x >> 6;
    const float bias = bo[col];
    for (int i = rr; i < 16; i += 4) {
        float sum = red[0][i][col] + red[1][i][col] + red[2][i][col] + red[3][i][col] + bias;
        out[(size_t)(r0 + i) * 64 + col] = sum;
    }
}

// ---------------------------------------------------------------------------
extern "C" void kernel_launch(void* const* d_in, const int* in_sizes, int n_in,
                              void* d_out, int out_size, void* d_ws, size_t ws_size,
                              hipStream_t stream)
{
    const float* x  = (const float*)d_in[0];
    const float* Wq = (const float*)d_in[1];
    const float* bq = (const float*)d_in[2];
    const float* Wk = (const float*)d_in[3];
    const float* bk = (const float*)d_in[4];
    const float* Wv = (const float*)d_in[5];
    const float* bv = (const float*)d_in[6];
    const float* Wo = (const float*)d_in[7];
    const float* bo = (const float*)d_in[8];
    float* out = (float*)d_out;

    char* w = (char*)d_ws;
    const size_t MB6 = (size_t)BB * HH * SS * DD * 2;   // 6 MB per tensor
    _Float16*       Q16 = (_Float16*)(w);
    _Float16*       K16 = (_Float16*)(w + MB6);
    unsigned short* VT  = (unsigned short*)(w + 2 * MB6);
    _Float16*       O16 = (_Float16*)(w + 3 * MB6);
    _Float16*       WoT = (_Float16*)(w + 4 * MB6);

    qkv_kernel<<<dim3(256, 9), 256, 0, stream>>>(x, Wq, bq, Wk, bk, Wv, bv, Wo, WoT, Q16, K16, VT);
    attn_kernel<<<dim3(64, BB * HH), 256, 0, stream>>>(Q16, K16, VT, O16);
    out_kernel<<<(BB * SS) / 16, 256, 0, stream>>>(O16, WoT, bo, out);
}

// Round 6
// 154.776 us; speedup vs baseline: 1.0873x; 1.0873x over previous
//
#include <hip/hip_runtime.h>
#include <math.h>

#define BB 2
#define SS 2048
#define DD 64
#define HH 12
#define CFIX 16.0f

typedef _Float16 v8h __attribute__((ext_vector_type(8)));
typedef short    v8s __attribute__((ext_vector_type(8)));
typedef short    v4s __attribute__((ext_vector_type(4)));
typedef float    v4f __attribute__((ext_vector_type(4)));

__device__ __forceinline__ unsigned short f2bf(float f) {
    unsigned u = __float_as_uint(f);
    u += 0x7FFF + ((u >> 16) & 1);          // RTN-even
    return (unsigned short)(u >> 16);
}
__device__ __forceinline__ unsigned short f2bf_trunc(float f) {
    return (unsigned short)(__float_as_uint(f) >> 16);   // p>=0; truncation bias cancels in o/l
}

__device__ __forceinline__ void async16(const void* g, void* l) {
    __builtin_amdgcn_global_load_lds(
        (const __attribute__((address_space(1))) unsigned int*)g,
        (__attribute__((address_space(3))) unsigned int*)l, 16, 0, 0);
}

// ---------------------------------------------------------------------------
// Kernel 1: fused QKV projection (+ WoT prep folded in).
// Outputs: Q16,K16 fp16 [bh][s][64]; VT bf16 [bh][d][s]; WoT fp16 [64][768].
// ---------------------------------------------------------------------------
__global__ __launch_bounds__(256) void qkv_kernel(
    const float* __restrict__ x,
    const float* __restrict__ Wq, const float* __restrict__ bq,
    const float* __restrict__ Wk, const float* __restrict__ bk,
    const float* __restrict__ Wv, const float* __restrict__ bv,
    const float* __restrict__ Wo, _Float16* __restrict__ WoT,
    _Float16* __restrict__ Q16, _Float16* __restrict__ K16,
    unsigned short* __restrict__ VT)
{
    __shared__ float xs[16 * 64];
    const int rBase = blockIdx.x * 16;
    const int cg    = blockIdx.y;
    const int mat   = cg / 3;
    const int col   = (cg % 3) * 256 + threadIdx.x;

    // folded prep: transpose+convert Wo (768x64 -> WoT[64][768])
    if (cg == 0 && blockIdx.x < 192) {
        int e = blockIdx.x * 256 + threadIdx.x;     // < 49152
        int k = e >> 6, c2 = e & 63;
        WoT[c2 * 768 + k] = (_Float16)Wo[e];
    }

    const float* W    = (mat == 0) ? Wq : (mat == 1) ? Wk : Wv;
    const float* bias = (mat == 0) ? bq : (mat == 1) ? bk : bv;

    for (int i = threadIdx.x; i < 16 * 64; i += 256)
        xs[i] = x[rBase * 64 + i];
    __syncthreads();

    float acc[16];
#pragma unroll
    for (int r = 0; r < 16; r++) acc[r] = 0.f;

    for (int k = 0; k < 64; k++) {
        float w = W[k * 768 + col];
#pragma unroll
        for (int r = 0; r < 16; r++) acc[r] += xs[r * 64 + k] * w;
    }

    const float bb = bias[col];
    const int h = col >> 6, d = col & 63;

    if (mat < 2) {
        _Float16* Out = (mat == 0) ? Q16 : K16;
#pragma unroll
        for (int r = 0; r < 16; r++) {
            int row = rBase + r;
            int b = row >> 11, s = row & 2047;
            Out[(((size_t)b * HH + h) * SS + s) * 64 + d] = (_Float16)(acc[r] + bb);
        }
    } else {
        const int b = rBase >> 11, s0 = rBase & 2047;   // 16 | 2048: no straddle
        unsigned short tmp[16];
#pragma unroll
        for (int r = 0; r < 16; r++) tmp[r] = f2bf(acc[r] + bb);
        size_t base = ((size_t)(b * HH + h) * 64 + d) * SS + s0;
        v8s w0, w1;
#pragma unroll
        for (int r = 0; r < 8; r++) { w0[r] = (short)tmp[r]; w1[r] = (short)tmp[r + 8]; }
        *(v8s*)&VT[base]     = w0;
        *(v8s*)&VT[base + 8] = w1;
    }
}

// ---------------------------------------------------------------------------
// Kernel 2: MFMA flash attention, fixed-C softmax, key-split waves.
// Block = 4 waves over 32 q rows: wave = (rowg = w&1 [16 rows], keyh = w>>1
// [32 of the 64 staged keys]). Partial (o,l) merged in epilogue.
// Grid (64, 24). qtile = (x + 11*y) & 63: breaks the x==c%64 CU-collision
// (64 | 256 round-robin) so each CU's 6 blocks get qtile offsets
// {0,44,24,4,48,28} -> per-CU work balanced to ~±17% (was ±100%).
// ---------------------------------------------------------------------------
__global__ __launch_bounds__(256, 4) void attn_kernel(
    const _Float16* __restrict__ Q16, const _Float16* __restrict__ K16,
    const unsigned short* __restrict__ VTg, _Float16* __restrict__ O16)
{
    __shared__ __align__(16) _Float16       Kl[2][64 * 64];   // [key][d], xor-swizzled
    __shared__ __align__(16) unsigned short Vl[2][64 * 64];   // [d][key], xor-swizzled
    __shared__ __align__(16) unsigned short Pl[4][16 * 36];   // stride 36: aligned + ~conflict-free

    const int bh    = blockIdx.y;
    const int qtile = (int)((blockIdx.x + 11 * blockIdx.y) & 63);   // CU-collision-breaking swizzle
    const int qBase = qtile * 32;
    const int wave  = threadIdx.x >> 6;
    const int lane  = threadIdx.x & 63;
    const int llow  = lane & 15;
    const int quad  = lane >> 4;
    const int rowg  = wave & 1;
    const int keyh  = wave >> 1;
    const int q0    = qBase + rowg * 16;

    const _Float16*       Kp = K16 + (size_t)bh * SS * 64;
    const unsigned short* Vp = VTg + (size_t)bh * 64 * SS;

    const _Float16* Qp = Q16 + ((size_t)bh * SS + q0) * 64;
    v8h qa0 = *(const v8h*)(Qp + llow * 64 + quad * 8);
    v8h qa1 = *(const v8h*)(Qp + llow * 64 + 32 + quad * 8);

    v4f o[4];
    float lacc[4] = {0.f, 0.f, 0.f, 0.f};
#pragma unroll
    for (int nb = 0; nb < 4; nb++) o[nb] = (v4f){0.f, 0.f, 0.f, 0.f};

    const int nt = qtile / 2 + 1;   // keys needed: <= 32*qtile+31 -> floor(qtile/2)+1 tiles

    // prefetch tile 0 into buf 0 (wave-uniform base + lane*16 dest, per DMA rule)
#pragma unroll
    for (int rep = 0; rep < 2; rep++) {
        int c = rep * 256 + threadIdx.x;
        int row = c >> 3, g = (c & 7) ^ (row & 7);
        async16(Kp + (size_t)row * 64 + g * 8, &Kl[0][(rep * 256 + wave * 64) * 8]);
        async16(Vp + (size_t)row * SS + g * 8, &Vl[0][(rep * 256 + wave * 64) * 8]);
    }

    for (int t = 0; t < nt; t++) {
        __syncthreads();                 // drains this tile's DMA
        if (t + 1 < nt) {                // prefetch AFTER barrier -> overlaps compute
            const int ktn = (t + 1) * 64, bufn = (t + 1) & 1;
#pragma unroll
            for (int rep = 0; rep < 2; rep++) {
                int c = rep * 256 + threadIdx.x;
                int row = c >> 3, g = (c & 7) ^ (row & 7);
                async16(Kp + (size_t)(ktn + row) * 64 + g * 8,
                        &Kl[bufn][(rep * 256 + wave * 64) * 8]);
                async16(Vp + (size_t)row * SS + ktn + g * 8,
                        &Vl[bufn][(rep * 256 + wave * 64) * 8]);
            }
        }
        const int buf = t & 1, kt = t * 64;
        const int sw = llow & 7;

        // ---- QK^T over this wave's 32-key half: 2 col-blocks of 16 ----
        v4f sc[2];
#pragma unroll
        for (int cb = 0; cb < 2; cb++) {
            const int rk = 32 * keyh + 16 * cb + llow;
            v8h k0 = *(const v8h*)&Kl[buf][rk * 64 + ((quad ^ sw)) * 8];
            v8h k1 = *(const v8h*)&Kl[buf][rk * 64 + (((4 + quad) ^ sw)) * 8];
            v4f a = (v4f){0.f, 0.f, 0.f, 0.f};
            a = __builtin_amdgcn_mfma_f32_16x16x32_f16(qa0, k0, a, 0, 0, 0);
            a = __builtin_amdgcn_mfma_f32_16x16x32_f16(qa1, k1, a, 0, 0, 0);
            sc[cb] = a;
        }

        // ---- mask folded into exp select; fixed-C; P write ----
#pragma unroll
        for (int cb = 0; cb < 2; cb++) {
            const int key = kt + 32 * keyh + 16 * cb + llow;
#pragma unroll
            for (int r = 0; r < 4; r++) {
                const int row = q0 + quad * 4 + r;
                const float sv = sc[cb][r];
                const float e  = __expf(sv - CFIX);
                const float p  = (key <= row && sv != 0.f) ? e : 0.f;  // faithful quirky mask
                lacc[r] += p;
                Pl[wave][(quad * 4 + r) * 36 + 16 * cb + llow] = f2bf_trunc(p);
            }
        }

        // ---- P: C-layout -> A-layout via per-wave LDS tile ----
        v8s pa;
        {
            v4s a0 = *(const v4s*)&Pl[wave][llow * 36 + quad * 8];
            v4s a1 = *(const v4s*)&Pl[wave][llow * 36 + quad * 8 + 4];
#pragma unroll
            for (int j = 0; j < 4; j++) { pa[j] = a0[j]; pa[j + 4] = a1[j]; }
        }

        // ---- PV over the 32-key half (bf16) ----
#pragma unroll
        for (int nb = 0; nb < 4; nb++) {
            const int rv = 16 * nb + llow;                       // rv&7 == sw
            v8s vv = *(const v8s*)&Vl[buf][rv * 64 + (((4 * keyh + quad) ^ sw)) * 8];
            o[nb] = __builtin_amdgcn_mfma_f32_16x16x32_bf16(pa, vv, o[nb], 0, 0, 0);
        }
    }

    // ---- epilogue ----
    // lacc[r] is a per-lane PARTIAL (keys == llow mod 16 of this wave's half):
    // reduce over the 16-lane group first.
#pragma unroll
    for (int r = 0; r < 4; r++) {
        lacc[r] += __shfl_xor(lacc[r], 1);
        lacc[r] += __shfl_xor(lacc[r], 2);
        lacc[r] += __shfl_xor(lacc[r], 4);
        lacc[r] += __shfl_xor(lacc[r], 8);
    }

    // merge key-halves via LDS (reuse K/V buffers), write O
    __syncthreads();                                  // last tile's LDS reads done
    float* redO = (float*)&Kl[0][0];                  // [32 rows][stride 68]
    float* redL = (float*)&Vl[0][0];                  // [32 rows]
    if (keyh == 1) {
#pragma unroll
        for (int nb = 0; nb < 4; nb++)
#pragma unroll
            for (int r = 0; r < 4; r++)
                redO[(rowg * 16 + quad * 4 + r) * 68 + 16 * nb + llow] = o[nb][r];
        if (llow == 0) {
#pragma unroll
            for (int r = 0; r < 4; r++)
                redL[rowg * 16 + quad * 4 + r] = lacc[r];     // full row sum (reduced above)
        }
    }
    __syncthreads();
    if (keyh == 0) {
        _Float16* Op = O16 + ((size_t)bh * SS + q0) * 64;
#pragma unroll
        for (int r = 0; r < 4; r++)
            lacc[r] += redL[rowg * 16 + quad * 4 + r];
#pragma unroll
        for (int nb = 0; nb < 4; nb++)
#pragma unroll
            for (int r = 0; r < 4; r++) {
                float v = o[nb][r] + redO[(rowg * 16 + quad * 4 + r) * 68 + 16 * nb + llow];
                Op[(quad * 4 + r) * 64 + 16 * nb + llow] = (_Float16)(v / lacc[r]);
            }
    }
}

// ---------------------------------------------------------------------------
// Kernel 3: output projection via MFMA (unchanged).
// ---------------------------------------------------------------------------
__global__ __launch_bounds__(256) void out_kernel(
    const _Float16* __restrict__ O16, const _Float16* __restrict__ WoT,
    const float* __restrict__ bo, float* __restrict__ out)
{
    __shared__ __align__(16) float red[4][16][66];
    const int r0   = blockIdx.x * 16;
    const int wave = threadIdx.x >> 6, lane = threadIdx.x & 63;
    const int llow = lane & 15, quad = lane >> 4;
    const int b = r0 >> 11, s = r0 & 2047;          // 16 | 2048: no straddle

    v4f acc[4];
#pragma unroll
    for (int cb = 0; cb < 4; cb++) acc[cb] = (v4f){0.f, 0.f, 0.f, 0.f};

#pragma unroll
    for (int i = 0; i < 6; i++) {
        const int kb = wave * 6 + i;                // 0..23
        const int h = kb >> 1, dseg = (kb & 1) * 32;
        v8h af = *(const v8h*)(O16 + ((size_t)(b * HH + h) * SS + s + llow) * 64 + dseg + quad * 8);
#pragma unroll
        for (int cb = 0; cb < 4; cb++) {
            v8h bf = *(const v8h*)(WoT + (size_t)(16 * cb + llow) * 768 + kb * 32 + quad * 8);
            acc[cb] = __builtin_amdgcn_mfma_f32_16x16x32_f16(af, bf, acc[cb], 0, 0, 0);
        }
    }

#pragma unroll
    for (int cb = 0; cb < 4; cb++)
#pragma unroll
        for (int r = 0; r < 4; r++)
            red[wave][quad * 4 + r][16 * cb + llow] = acc[cb][r];
    __syncthreads();

    const int col = threadIdx.x & 63, rr = threadIdx.x >> 6;
    const float bias = bo[col];
    for (int i = rr; i < 16; i += 4) {
        float sum = red[0][i][col] + red[1][i][col] + red[2][i][col] + red[3][i][col] + bias;
        out[(size_t)(r0 + i) * 64 + col] = sum;
    }
}

// ---------------------------------------------------------------------------
extern "C" void kernel_launch(void* const* d_in, const int* in_sizes, int n_in,
                              void* d_out, int out_size, void* d_ws, size_t ws_size,
                              hipStream_t stream)
{
    const float* x  = (const float*)d_in[0];
    const float* Wq = (const float*)d_in[1];
    const float* bq = (const float*)d_in[2];
    const float* Wk = (const float*)d_in[3];
    const float* bk = (const float*)d_in[4];
    const float* Wv = (const float*)d_in[5];
    const float* bv = (const float*)d_in[6];
    const float* Wo = (const float*)d_in[7];
    const float* bo = (const float*)d_in[8];
    float* out = (float*)d_out;

    char* w = (char*)d_ws;
    const size_t MB6 = (size_t)BB * HH * SS * DD * 2;   // 6 MB per tensor
    _Float16*       Q16 = (_Float16*)(w);
    _Float16*       K16 = (_Float16*)(w + MB6);
    unsigned short* VT  = (unsigned short*)(w + 2 * MB6);
    _Float16*       O16 = (_Float16*)(w + 3 * MB6);
    _Float16*       WoT = (_Float16*)(w + 4 * MB6);

    qkv_kernel<<<dim3(256, 9), 256, 0, stream>>>(x, Wq, bq, Wk, bk, Wv, bv, Wo, WoT, Q16, K16, VT);
    attn_kernel<<<dim3(64, BB * HH), 256, 0, stream>>>(Q16, K16, VT, O16);
    out_kernel<<<(BB * SS) / 16, 256, 0, stream>>>(O16, WoT, bo, out);
}